// Round 2
// baseline (639.602 us; speedup 1.0000x reference)
//
#include <hip/hip_runtime.h>
#include <stdint.h>

typedef __bf16 bf16_t;
typedef bf16_t bf16x8 __attribute__((ext_vector_type(8)));
typedef float  f32x4  __attribute__((ext_vector_type(4)));

static constexpr uint32_t PRIME = 2654435761u;
static constexpr uint32_t HMASK = (1u << 17) - 1u;   // HASHMAP_SIZE - 1

// One wave = one 16-point tile per iteration. All data fp32; bf16 only at the
// MFMA boundary (threshold is 2% of refmax -- bf16 quantization noise ~1e-3).
// Lane decomposition: q = lane>>4 (quad), n16 = lane&15.
// Encode: lane (q,n16) computes levels 4q..4q+3 of point n16 -> exactly the
// mfma_f32_16x16x32_bf16 A-fragment (A[m=lane&15][k=q*8+j], k=2*level+f).
// Weights live in registers as B-fragments for the whole kernel (~56 VGPRs).
// C/D layout col=lane&15, row=q*4+reg -> bias broadcast into C init is free.
__global__ __launch_bounds__(256)
void fused_hash_mlp(const float* __restrict__ xin,
                    const float* __restrict__ enc,
                    const float* __restrict__ w0, const float* __restrict__ b0,
                    const float* __restrict__ w1, const float* __restrict__ b1,
                    const float* __restrict__ w2, const float* __restrict__ b2,
                    float* __restrict__ out,
                    int nGroups)
{
    // per-wave 16x64 bf16 transpose tile, stride 80 (160B rows keeps the
    // ds_read_b128 16B-aligned; 4-way bank conflict only ~1.58x, negligible)
    __shared__ __align__(16) bf16_t lds[4 * 16 * 80];

    const int tid  = threadIdx.x;
    const int wib  = tid >> 6;      // wave in block (0..3)
    const int lane = tid & 63;
    const int q    = lane >> 4;
    const int n16  = lane & 15;

    bf16_t* myLds = &lds[wib * (16 * 80)];

    // ---- weight B-fragments (fp32 -> bf16 once; ~56 VGPRs) ----
    bf16x8 Bw0[4], Bw1[2][4], Bw2[2];
#pragma unroll
    for (int t = 0; t < 4; ++t)
#pragma unroll
        for (int j = 0; j < 8; ++j)
            Bw0[t][j] = (bf16_t)w0[(q * 8 + j) * 64 + t * 16 + n16];
#pragma unroll
    for (int c = 0; c < 2; ++c)
#pragma unroll
        for (int t = 0; t < 4; ++t)
#pragma unroll
            for (int j = 0; j < 8; ++j)
                Bw1[c][t][j] = (bf16_t)w1[(c * 32 + q * 8 + j) * 64 + t * 16 + n16];
#pragma unroll
    for (int c = 0; c < 2; ++c)
#pragma unroll
        for (int j = 0; j < 8; ++j)
            Bw2[c][j] = (n16 < 3) ? (bf16_t)w2[(c * 32 + q * 8 + j) * 3 + n16]
                                  : (bf16_t)0.0f;

    float bv0[4], bv1[4];
#pragma unroll
    for (int t = 0; t < 4; ++t) {
        bv0[t] = b0[t * 16 + n16];
        bv1[t] = b1[t * 16 + n16];
    }
    const float bv2 = (n16 < 3) ? b2[n16] : 0.0f;

    // scales for levels 4q..4q+3: 16*1.5^l = 3^l * 2^(4-l) is EXACT in fp32
    // (3^15 < 2^24), so pos/floor/hash bit-match the fp32 numpy reference.
    const float sb = 16.0f * ((q == 0) ? 1.0f :
                              (q == 1) ? 5.0625f :           // 1.5^4
                              (q == 2) ? 25.62890625f :      // 1.5^8
                                         129.746337890625f); // 1.5^12
    const float sc[4] = { sb, sb * 1.5f, sb * 2.25f, sb * 3.375f };

    const char* encB = (const char*)enc;
    // byte offset of level 4q inside the 128B (16 lvl x 2 feat x 4B) entry
    const uint32_t lvBase = (uint32_t)q * 32u;

    for (int g = blockIdx.x; g < nGroups; g += gridDim.x) {
        const int tile = g * 4 + wib;
        const int p = tile * 16 + n16;
        const float2 xy = ((const float2*)xin)[p];
        const float px = xy.x, py = xy.y;

        // ---- hash-grid encode: 4 levels x 4 corner float2 gathers per lane ----
        bf16x8 af;
#pragma unroll
        for (int lv = 0; lv < 4; ++lv) {
            const float posx = px * sc[lv], posy = py * sc[lv];
            const float fx = floorf(posx), fy = floorf(posy);
            const float frx = posx - fx,  fry = posy - fy;
            const uint32_t ix = (uint32_t)fx, iy = (uint32_t)fy;
            const uint32_t hy0 = iy * PRIME, hy1 = hy0 + PRIME;  // (iy+1)*P mod 2^32
            const uint32_t i00 = ( ix       ^ hy0) & HMASK;
            const uint32_t i10 = ((ix + 1u) ^ hy0) & HMASK;
            const uint32_t i01 = ( ix       ^ hy1) & HMASK;
            const uint32_t i11 = ((ix + 1u) ^ hy1) & HMASK;
            const uint32_t off = lvBase + (uint32_t)lv * 8u;
            // entry stride = L*F*4B = 128B; one float2 = both features
            const float2 e00 = *(const float2*)(encB + (i00 * 128u + off));
            const float2 e10 = *(const float2*)(encB + (i10 * 128u + off));
            const float2 e01 = *(const float2*)(encB + (i01 * 128u + off));
            const float2 e11 = *(const float2*)(encB + (i11 * 128u + off));
            const float wx1 = frx, wx0 = 1.0f - frx, wy1 = fry, wy0 = 1.0f - fry;
            const float w00 = wx0 * wy0, w10 = wx1 * wy0, w01 = wx0 * wy1, w11 = wx1 * wy1;
            const float f0 = w00 * e00.x + w10 * e10.x + w01 * e01.x + w11 * e11.x;
            const float f1 = w00 * e00.y + w10 * e10.y + w01 * e01.y + w11 * e11.y;
            af[2 * lv]     = (bf16_t)f0;
            af[2 * lv + 1] = (bf16_t)f1;
        }

        // ---- layer 0: [16x32] @ [32x64] + b0, relu ----
        f32x4 c0[4];
#pragma unroll
        for (int t = 0; t < 4; ++t) {
            f32x4 cc = { bv0[t], bv0[t], bv0[t], bv0[t] };
            c0[t] = __builtin_amdgcn_mfma_f32_16x16x32_bf16(af, Bw0[t], cc, 0, 0, 0);
        }

        // C-layout -> A-layout via per-wave LDS tile (no cross-wave sharing)
        __syncthreads();
#pragma unroll
        for (int t = 0; t < 4; ++t)
#pragma unroll
            for (int r = 0; r < 4; ++r)
                myLds[(q * 4 + r) * 80 + t * 16 + n16] = (bf16_t)fmaxf(c0[t][r], 0.0f);
        __syncthreads();

        bf16x8 A1[2];
#pragma unroll
        for (int c = 0; c < 2; ++c)
            A1[c] = *(const bf16x8*)&myLds[n16 * 80 + c * 32 + q * 8];

        // ---- layer 1: [16x64] @ [64x64] + b1, relu ----
        f32x4 c1[4];
#pragma unroll
        for (int t = 0; t < 4; ++t) {
            f32x4 cc = { bv1[t], bv1[t], bv1[t], bv1[t] };
            cc    = __builtin_amdgcn_mfma_f32_16x16x32_bf16(A1[0], Bw1[0][t], cc, 0, 0, 0);
            c1[t] = __builtin_amdgcn_mfma_f32_16x16x32_bf16(A1[1], Bw1[1][t], cc, 0, 0, 0);
        }

        __syncthreads();
#pragma unroll
        for (int t = 0; t < 4; ++t)
#pragma unroll
            for (int r = 0; r < 4; ++r)
                myLds[(q * 4 + r) * 80 + t * 16 + n16] = (bf16_t)fmaxf(c1[t][r], 0.0f);
        __syncthreads();

        bf16x8 A2[2];
#pragma unroll
        for (int c = 0; c < 2; ++c)
            A2[c] = *(const bf16x8*)&myLds[n16 * 80 + c * 32 + q * 8];

        // ---- layer 2: [16x64] @ [64x3 padded to 16] + b2 (no relu) ----
        f32x4 co = { bv2, bv2, bv2, bv2 };
        co = __builtin_amdgcn_mfma_f32_16x16x32_bf16(A2[0], Bw2[0], co, 0, 0, 0);
        co = __builtin_amdgcn_mfma_f32_16x16x32_bf16(A2[1], Bw2[1], co, 0, 0, 0);

        if (n16 < 3) {
#pragma unroll
            for (int r = 0; r < 4; ++r)
                out[(size_t)(tile * 16 + q * 4 + r) * 3 + n16] = co[r];
        }
    }
}

extern "C" void kernel_launch(void* const* d_in, const int* in_sizes, int n_in,
                              void* d_out, int out_size, void* d_ws, size_t ws_size,
                              hipStream_t stream) {
    const float* x  = (const float*)d_in[0];
    const float* en = (const float*)d_in[1];
    const float* w0 = (const float*)d_in[2];
    const float* b0 = (const float*)d_in[3];
    const float* w1 = (const float*)d_in[4];
    const float* b1 = (const float*)d_in[5];
    const float* w2 = (const float*)d_in[6];
    const float* b2 = (const float*)d_in[7];
    float* out = (float*)d_out;

    const int N = in_sizes[0] / 2;      // 2^20 points
    const int nTiles  = N / 16;         // 65536
    const int nGroups = nTiles / 4;     // 16384 (4 waves/block, 1 tile each)
    int blocks = 2048;
    if (blocks > nGroups) blocks = nGroups;
    fused_hash_mlp<<<blocks, 256, 0, stream>>>(x, en, w0, b0, w1, b1, w2, b2, out, nGroups);
}

// Round 3
// 320.154 us; speedup vs baseline: 1.9978x; 1.9978x over previous
//
#include <hip/hip_runtime.h>
#include <stdint.h>

typedef __bf16 bf16_t;
typedef bf16_t bf16x8 __attribute__((ext_vector_type(8)));
typedef float  f32x4  __attribute__((ext_vector_type(4)));

static constexpr uint32_t PRIME = 2654435761u;
static constexpr uint32_t HMASK = (1u << 17) - 1u;   // HASHMAP_SIZE - 1
static constexpr uint32_t TSIZE = 1u << 17;

__device__ __forceinline__ float bflo(uint32_t u) {
    union { uint32_t i; float f; } v; v.i = u << 16; return v.f;
}
__device__ __forceinline__ float bfhi(uint32_t u) {
    union { uint32_t i; float f; } v; v.i = u & 0xffff0000u; return v.f;
}
__device__ __forceinline__ uint16_t bfbits(float f) {
    union { bf16_t h; uint16_t u; } v; v.h = (bf16_t)f; return v.u;
}

// ---- prepass: repack fp32 [T][L][F] table -> bf16-pair dwords, level-major [L][T]
// (8.4 MB in d_ws). 4B entries give x-corner line sharing + per-level locality.
__global__ __launch_bounds__(256)
void repack_enc(const float2* __restrict__ src, uint32_t* __restrict__ dst) {
    const int tid = blockIdx.x * blockDim.x + threadIdx.x;   // 0 .. 2^21-1
    const float2 f = src[tid];                // src float2 index = t*16 + l = tid
    const int t = tid >> 4, l = tid & 15;
    dst[((uint32_t)l << 17) + t] = (uint32_t)bfbits(f.x) | ((uint32_t)bfbits(f.y) << 16);
}

// One wave = one 16-point tile per iteration. q = lane>>4, n16 = lane&15.
// Lane (q,n16) computes levels 4q..4q+3 of point n16 -> exactly the
// mfma_f32_16x16x32_bf16 A-fragment (A[m=lane&15][k=q*8+j], k=2*level+f).
// Weights live in registers as B-fragments for the whole kernel.
// C/D layout col=lane&15, row=q*4+reg -> bias broadcast into C init is free.
__global__ __launch_bounds__(256)
void fused_hash_mlp(const float* __restrict__ xin,
                    const uint32_t* __restrict__ tab,   // level-major bf16-pair table
                    const float* __restrict__ w0, const float* __restrict__ b0,
                    const float* __restrict__ w1, const float* __restrict__ b1,
                    const float* __restrict__ w2, const float* __restrict__ b2,
                    float* __restrict__ out,
                    int nGroups)
{
    __shared__ __align__(16) bf16_t lds[4 * 16 * 80];

    const int tid  = threadIdx.x;
    const int wib  = tid >> 6;
    const int lane = tid & 63;
    const int q    = lane >> 4;
    const int n16  = lane & 15;

    bf16_t* myLds = &lds[wib * (16 * 80)];

    // ---- weight B-fragments (fp32 -> bf16 once; ~56 VGPRs) ----
    bf16x8 Bw0[4], Bw1[2][4], Bw2[2];
#pragma unroll
    for (int t = 0; t < 4; ++t)
#pragma unroll
        for (int j = 0; j < 8; ++j)
            Bw0[t][j] = (bf16_t)w0[(q * 8 + j) * 64 + t * 16 + n16];
#pragma unroll
    for (int c = 0; c < 2; ++c)
#pragma unroll
        for (int t = 0; t < 4; ++t)
#pragma unroll
            for (int j = 0; j < 8; ++j)
                Bw1[c][t][j] = (bf16_t)w1[(c * 32 + q * 8 + j) * 64 + t * 16 + n16];
#pragma unroll
    for (int c = 0; c < 2; ++c)
#pragma unroll
        for (int j = 0; j < 8; ++j)
            Bw2[c][j] = (n16 < 3) ? (bf16_t)w2[(c * 32 + q * 8 + j) * 3 + n16]
                                  : (bf16_t)0.0f;

    float bv0[4], bv1[4];
#pragma unroll
    for (int t = 0; t < 4; ++t) {
        bv0[t] = b0[t * 16 + n16];
        bv1[t] = b1[t * 16 + n16];
    }
    const float bv2 = (n16 < 3) ? b2[n16] : 0.0f;

    // scales for levels 4q..4q+3: 16*1.5^l = 3^l * 2^(4-l) is EXACT in fp32,
    // so pos/floor/hash bit-match the fp32 numpy reference.
    const float sb = 16.0f * ((q == 0) ? 1.0f :
                              (q == 1) ? 5.0625f :           // 1.5^4
                              (q == 2) ? 25.62890625f :      // 1.5^8
                                         129.746337890625f); // 1.5^12
    const float sc[4] = { sb, sb * 1.5f, sb * 2.25f, sb * 3.375f };

    const uint32_t* tq = tab + ((uint32_t)q * 4u << 17);   // level 4q sub-table

    for (int g = blockIdx.x; g < nGroups; g += gridDim.x) {
        const int tile = g * 4 + wib;
        const int p = tile * 16 + n16;
        const float2 xy = ((const float2*)xin)[p];
        const float px = xy.x, py = xy.y;

        // ---- hash-grid encode: 4 levels x 4 corner dword gathers per lane ----
        bf16x8 af;
#pragma unroll
        for (int lv = 0; lv < 4; ++lv) {
            const float posx = px * sc[lv], posy = py * sc[lv];
            const float fx = floorf(posx), fy = floorf(posy);
            const float frx = posx - fx,  fry = posy - fy;
            const uint32_t ix = (uint32_t)fx, iy = (uint32_t)fy;
            const uint32_t hy0 = iy * PRIME, hy1 = hy0 + PRIME;  // (iy+1)*P mod 2^32
            const uint32_t i00 = ( ix       ^ hy0) & HMASK;
            const uint32_t i10 = ((ix + 1u) ^ hy0) & HMASK;
            const uint32_t i01 = ( ix       ^ hy1) & HMASK;
            const uint32_t i11 = ((ix + 1u) ^ hy1) & HMASK;
            const uint32_t base = (uint32_t)lv << 17;
            const uint32_t u00 = tq[base + i00];
            const uint32_t u10 = tq[base + i10];
            const uint32_t u01 = tq[base + i01];
            const uint32_t u11 = tq[base + i11];
            const float wx1 = frx, wx0 = 1.0f - frx, wy1 = fry, wy0 = 1.0f - fry;
            const float w00 = wx0 * wy0, w10 = wx1 * wy0, w01 = wx0 * wy1, w11 = wx1 * wy1;
            const float f0 = w00 * bflo(u00) + w10 * bflo(u10) + w01 * bflo(u01) + w11 * bflo(u11);
            const float f1 = w00 * bfhi(u00) + w10 * bfhi(u10) + w01 * bfhi(u01) + w11 * bfhi(u11);
            af[2 * lv]     = (bf16_t)f0;
            af[2 * lv + 1] = (bf16_t)f1;
        }

        // ---- layer 0: [16x32] @ [32x64] + b0, relu ----
        f32x4 c0[4];
#pragma unroll
        for (int t = 0; t < 4; ++t) {
            f32x4 cc = { bv0[t], bv0[t], bv0[t], bv0[t] };
            c0[t] = __builtin_amdgcn_mfma_f32_16x16x32_bf16(af, Bw0[t], cc, 0, 0, 0);
        }

        __syncthreads();
#pragma unroll
        for (int t = 0; t < 4; ++t)
#pragma unroll
            for (int r = 0; r < 4; ++r)
                myLds[(q * 4 + r) * 80 + t * 16 + n16] = (bf16_t)fmaxf(c0[t][r], 0.0f);
        __syncthreads();

        bf16x8 A1[2];
#pragma unroll
        for (int c = 0; c < 2; ++c)
            A1[c] = *(const bf16x8*)&myLds[n16 * 80 + c * 32 + q * 8];

        // ---- layer 1: [16x64] @ [64x64] + b1, relu ----
        f32x4 c1[4];
#pragma unroll
        for (int t = 0; t < 4; ++t) {
            f32x4 cc = { bv1[t], bv1[t], bv1[t], bv1[t] };
            cc    = __builtin_amdgcn_mfma_f32_16x16x32_bf16(A1[0], Bw1[0][t], cc, 0, 0, 0);
            c1[t] = __builtin_amdgcn_mfma_f32_16x16x32_bf16(A1[1], Bw1[1][t], cc, 0, 0, 0);
        }

        __syncthreads();
#pragma unroll
        for (int t = 0; t < 4; ++t)
#pragma unroll
            for (int r = 0; r < 4; ++r)
                myLds[(q * 4 + r) * 80 + t * 16 + n16] = (bf16_t)fmaxf(c1[t][r], 0.0f);
        __syncthreads();

        bf16x8 A2[2];
#pragma unroll
        for (int c = 0; c < 2; ++c)
            A2[c] = *(const bf16x8*)&myLds[n16 * 80 + c * 32 + q * 8];

        // ---- layer 2: [16x64] @ [64x3 padded to 16] + b2 (no relu) ----
        f32x4 co = { bv2, bv2, bv2, bv2 };
        co = __builtin_amdgcn_mfma_f32_16x16x32_bf16(A2[0], Bw2[0], co, 0, 0, 0);
        co = __builtin_amdgcn_mfma_f32_16x16x32_bf16(A2[1], Bw2[1], co, 0, 0, 0);

        if (n16 < 3) {
#pragma unroll
            for (int r = 0; r < 4; ++r)
                out[(size_t)(tile * 16 + q * 4 + r) * 3 + n16] = co[r];
        }
    }
}

// ---- fallback (R2 known-good): direct fp32 gather, used only if ws too small
__global__ __launch_bounds__(256)
void fused_hash_mlp_fp32(const float* __restrict__ xin,
                         const float* __restrict__ enc,
                         const float* __restrict__ w0, const float* __restrict__ b0,
                         const float* __restrict__ w1, const float* __restrict__ b1,
                         const float* __restrict__ w2, const float* __restrict__ b2,
                         float* __restrict__ out,
                         int nGroups)
{
    __shared__ __align__(16) bf16_t lds[4 * 16 * 80];
    const int tid  = threadIdx.x;
    const int wib  = tid >> 6;
    const int lane = tid & 63;
    const int q    = lane >> 4;
    const int n16  = lane & 15;
    bf16_t* myLds = &lds[wib * (16 * 80)];

    bf16x8 Bw0[4], Bw1[2][4], Bw2[2];
#pragma unroll
    for (int t = 0; t < 4; ++t)
#pragma unroll
        for (int j = 0; j < 8; ++j)
            Bw0[t][j] = (bf16_t)w0[(q * 8 + j) * 64 + t * 16 + n16];
#pragma unroll
    for (int c = 0; c < 2; ++c)
#pragma unroll
        for (int t = 0; t < 4; ++t)
#pragma unroll
            for (int j = 0; j < 8; ++j)
                Bw1[c][t][j] = (bf16_t)w1[(c * 32 + q * 8 + j) * 64 + t * 16 + n16];
#pragma unroll
    for (int c = 0; c < 2; ++c)
#pragma unroll
        for (int j = 0; j < 8; ++j)
            Bw2[c][j] = (n16 < 3) ? (bf16_t)w2[(c * 32 + q * 8 + j) * 3 + n16]
                                  : (bf16_t)0.0f;

    float bv0[4], bv1[4];
#pragma unroll
    for (int t = 0; t < 4; ++t) { bv0[t] = b0[t * 16 + n16]; bv1[t] = b1[t * 16 + n16]; }
    const float bv2 = (n16 < 3) ? b2[n16] : 0.0f;

    const float sb = 16.0f * ((q == 0) ? 1.0f : (q == 1) ? 5.0625f :
                              (q == 2) ? 25.62890625f : 129.746337890625f);
    const float sc[4] = { sb, sb * 1.5f, sb * 2.25f, sb * 3.375f };
    const char* encB = (const char*)enc;
    const uint32_t lvBase = (uint32_t)q * 32u;

    for (int g = blockIdx.x; g < nGroups; g += gridDim.x) {
        const int tile = g * 4 + wib;
        const int p = tile * 16 + n16;
        const float2 xy = ((const float2*)xin)[p];
        const float px = xy.x, py = xy.y;

        bf16x8 af;
#pragma unroll
        for (int lv = 0; lv < 4; ++lv) {
            const float posx = px * sc[lv], posy = py * sc[lv];
            const float fx = floorf(posx), fy = floorf(posy);
            const float frx = posx - fx,  fry = posy - fy;
            const uint32_t ix = (uint32_t)fx, iy = (uint32_t)fy;
            const uint32_t hy0 = iy * PRIME, hy1 = hy0 + PRIME;
            const uint32_t i00 = ( ix       ^ hy0) & HMASK;
            const uint32_t i10 = ((ix + 1u) ^ hy0) & HMASK;
            const uint32_t i01 = ( ix       ^ hy1) & HMASK;
            const uint32_t i11 = ((ix + 1u) ^ hy1) & HMASK;
            const uint32_t off = lvBase + (uint32_t)lv * 8u;
            const float2 e00 = *(const float2*)(encB + (i00 * 128u + off));
            const float2 e10 = *(const float2*)(encB + (i10 * 128u + off));
            const float2 e01 = *(const float2*)(encB + (i01 * 128u + off));
            const float2 e11 = *(const float2*)(encB + (i11 * 128u + off));
            const float wx1 = frx, wx0 = 1.0f - frx, wy1 = fry, wy0 = 1.0f - fry;
            const float w00 = wx0 * wy0, w10 = wx1 * wy0, w01 = wx0 * wy1, w11 = wx1 * wy1;
            af[2 * lv]     = (bf16_t)(w00 * e00.x + w10 * e10.x + w01 * e01.x + w11 * e11.x);
            af[2 * lv + 1] = (bf16_t)(w00 * e00.y + w10 * e10.y + w01 * e01.y + w11 * e11.y);
        }

        f32x4 c0[4];
#pragma unroll
        for (int t = 0; t < 4; ++t) {
            f32x4 cc = { bv0[t], bv0[t], bv0[t], bv0[t] };
            c0[t] = __builtin_amdgcn_mfma_f32_16x16x32_bf16(af, Bw0[t], cc, 0, 0, 0);
        }
        __syncthreads();
#pragma unroll
        for (int t = 0; t < 4; ++t)
#pragma unroll
            for (int r = 0; r < 4; ++r)
                myLds[(q * 4 + r) * 80 + t * 16 + n16] = (bf16_t)fmaxf(c0[t][r], 0.0f);
        __syncthreads();
        bf16x8 A1[2];
#pragma unroll
        for (int c = 0; c < 2; ++c)
            A1[c] = *(const bf16x8*)&myLds[n16 * 80 + c * 32 + q * 8];

        f32x4 c1[4];
#pragma unroll
        for (int t = 0; t < 4; ++t) {
            f32x4 cc = { bv1[t], bv1[t], bv1[t], bv1[t] };
            cc    = __builtin_amdgcn_mfma_f32_16x16x32_bf16(A1[0], Bw1[0][t], cc, 0, 0, 0);
            c1[t] = __builtin_amdgcn_mfma_f32_16x16x32_bf16(A1[1], Bw1[1][t], cc, 0, 0, 0);
        }
        __syncthreads();
#pragma unroll
        for (int t = 0; t < 4; ++t)
#pragma unroll
            for (int r = 0; r < 4; ++r)
                myLds[(q * 4 + r) * 80 + t * 16 + n16] = (bf16_t)fmaxf(c1[t][r], 0.0f);
        __syncthreads();
        bf16x8 A2[2];
#pragma unroll
        for (int c = 0; c < 2; ++c)
            A2[c] = *(const bf16x8*)&myLds[n16 * 80 + c * 32 + q * 8];

        f32x4 co = { bv2, bv2, bv2, bv2 };
        co = __builtin_amdgcn_mfma_f32_16x16x32_bf16(A2[0], Bw2[0], co, 0, 0, 0);
        co = __builtin_amdgcn_mfma_f32_16x16x32_bf16(A2[1], Bw2[1], co, 0, 0, 0);
        if (n16 < 3) {
#pragma unroll
            for (int r = 0; r < 4; ++r)
                out[(size_t)(tile * 16 + q * 4 + r) * 3 + n16] = co[r];
        }
    }
}

extern "C" void kernel_launch(void* const* d_in, const int* in_sizes, int n_in,
                              void* d_out, int out_size, void* d_ws, size_t ws_size,
                              hipStream_t stream) {
    const float* x  = (const float*)d_in[0];
    const float* en = (const float*)d_in[1];
    const float* w0 = (const float*)d_in[2];
    const float* b0 = (const float*)d_in[3];
    const float* w1 = (const float*)d_in[4];
    const float* b1 = (const float*)d_in[5];
    const float* w2 = (const float*)d_in[6];
    const float* b2 = (const float*)d_in[7];
    float* out = (float*)d_out;

    const int N = in_sizes[0] / 2;      // 2^20 points
    const int nTiles  = N / 16;
    const int nGroups = nTiles / 4;     // 16384

    const size_t wsNeeded = (size_t)TSIZE * 16 * 4;   // 8.4 MB
    if (ws_size >= wsNeeded) {
        uint32_t* tab = (uint32_t*)d_ws;
        repack_enc<<<(TSIZE * 16) / 256, 256, 0, stream>>>((const float2*)en, tab);
        int blocks = 4096;
        if (blocks > nGroups) blocks = nGroups;
        fused_hash_mlp<<<blocks, 256, 0, stream>>>(x, tab, w0, b0, w1, b1, w2, b2, out, nGroups);
    } else {
        int blocks = 2048;
        if (blocks > nGroups) blocks = nGroups;
        fused_hash_mlp_fp32<<<blocks, 256, 0, stream>>>(x, en, w0, b0, w1, b1, w2, b2, out, nGroups);
    }
}

// Round 4
// 258.478 us; speedup vs baseline: 2.4745x; 1.2386x over previous
//
#include <hip/hip_runtime.h>
#include <stdint.h>

typedef __bf16 bf16_t;
typedef bf16_t bf16x8 __attribute__((ext_vector_type(8)));
typedef float  f32x4  __attribute__((ext_vector_type(4)));

static constexpr uint32_t PRIME = 2654435761u;
static constexpr uint32_t HMASK = (1u << 17) - 1u;   // HASHMAP_SIZE - 1
static constexpr uint32_t TSIZE = 1u << 17;
static constexpr int      NDENSE = 12032;            // levels 0..4 dense entries

__device__ __forceinline__ float bflo(uint32_t u) {
    union { uint32_t i; float f; } v; v.i = u << 16; return v.f;
}
__device__ __forceinline__ float bfhi(uint32_t u) {
    union { uint32_t i; float f; } v; v.i = u & 0xffff0000u; return v.f;
}
__device__ __forceinline__ uint32_t bfbits(float f) {
    union { bf16_t h; uint16_t u; } v; v.h = (bf16_t)f; return (uint32_t)v.u;
}

// ---- prepass A: repack fp32 [T][L][F] -> bf16-pair dwords, level-major [L][T]
__global__ __launch_bounds__(256)
void repack_enc(const float2* __restrict__ src, uint32_t* __restrict__ dst) {
    const int tid = blockIdx.x * blockDim.x + threadIdx.x;   // 0 .. 2^21-1
    const float2 f = src[tid];                // src float2 index = t*16 + l
    const int t = tid >> 4, l = tid & 15;
    dst[((uint32_t)l << 17) + t] = bfbits(f.x) | (bfbits(f.y) << 16);
}

// ---- prepass B: dense mini-grids for levels 0..4 (scales 16,24,36,54,81).
// Grid widths W = scale+1 (corner reach): 17,25,37,55,82 -> 12032 entries, 48KB.
__global__ __launch_bounds__(256)
void densify_enc(const float2* __restrict__ src, uint32_t* __restrict__ dst) {
    const int i = blockIdx.x * 256 + threadIdx.x;   // 47*256 == 12032 exactly
    int lvl, W, off;
    if      (i <  289) { lvl = 0; W = 17; off = 0;    }
    else if (i <  914) { lvl = 1; W = 25; off = 289;  }
    else if (i < 2283) { lvl = 2; W = 37; off = 914;  }
    else if (i < 5308) { lvl = 3; W = 55; off = 2283; }
    else               { lvl = 4; W = 82; off = 5308; }
    const int li = i - off;
    const uint32_t iy = (uint32_t)(li / W), ix = (uint32_t)(li % W);
    const uint32_t h = (ix ^ (iy * PRIME)) & HMASK;
    const float2 f = src[h * 16 + lvl];
    dst[i] = bfbits(f.x) | (bfbits(f.y) << 16);
}

// One wave = one 16-point tile per iteration. q = lane>>4, n16 = lane&15.
// Lane (q,n16) computes levels 4q..4q+3 of point n16 -> exactly the
// mfma_f32_16x16x32_bf16 A-fragment (A[m=lane&15][k=q*8+j], k=2*level+f).
// Levels 0..4 are gathered from a 48KB dense LDS cache (removes 31% of the
// divergent global addresses + L1 pollution); levels 5..15 from the
// level-major bf16 table. Weights live in registers as B-fragments.
__global__ __launch_bounds__(256, 2)
void fused_hash_mlp(const float* __restrict__ xin,
                    const uint32_t* __restrict__ tab,    // hashed, level-major
                    const uint32_t* __restrict__ dense,  // dense lv0..4
                    const float* __restrict__ w0, const float* __restrict__ b0,
                    const float* __restrict__ w1, const float* __restrict__ b1,
                    const float* __restrict__ w2, const float* __restrict__ b2,
                    float* __restrict__ out,
                    int nGroups)
{
    __shared__ uint32_t ldsTab[NDENSE];                  // 48128 B
    __shared__ __align__(16) bf16_t lds[4 * 16 * 80];    // 10240 B transpose tiles

    const int tid  = threadIdx.x;
    const int wib  = tid >> 6;
    const int lane = tid & 63;
    const int q    = lane >> 4;
    const int n16  = lane & 15;

    bf16_t* myLds = &lds[wib * (16 * 80)];

    // cooperative fill of the dense level cache
    for (int i = tid; i < NDENSE; i += 256) ldsTab[i] = dense[i];

    // ---- weight B-fragments (fp32 -> bf16 once) ----
    bf16x8 Bw0[4], Bw1[2][4], Bw2[2];
#pragma unroll
    for (int t = 0; t < 4; ++t)
#pragma unroll
        for (int j = 0; j < 8; ++j)
            Bw0[t][j] = (bf16_t)w0[(q * 8 + j) * 64 + t * 16 + n16];
#pragma unroll
    for (int c = 0; c < 2; ++c)
#pragma unroll
        for (int t = 0; t < 4; ++t)
#pragma unroll
            for (int j = 0; j < 8; ++j)
                Bw1[c][t][j] = (bf16_t)w1[(c * 32 + q * 8 + j) * 64 + t * 16 + n16];
#pragma unroll
    for (int c = 0; c < 2; ++c)
#pragma unroll
        for (int j = 0; j < 8; ++j)
            Bw2[c][j] = (n16 < 3) ? (bf16_t)w2[(c * 32 + q * 8 + j) * 3 + n16]
                                  : (bf16_t)0.0f;

    float bv0[4], bv1[4];
#pragma unroll
    for (int t = 0; t < 4; ++t) {
        bv0[t] = b0[t * 16 + n16];
        bv1[t] = b1[t * 16 + n16];
    }
    const float bv2 = (n16 < 3) ? b2[n16] : 0.0f;

    // scales for levels 4q..4q+3: 16*1.5^l = 3^l * 2^(4-l) is EXACT in fp32,
    // so pos/floor/hash bit-match the fp32 numpy reference.
    const float sb = 16.0f * ((q == 0) ? 1.0f :
                              (q == 1) ? 5.0625f :           // 1.5^4
                              (q == 2) ? 25.62890625f :      // 1.5^8
                                         129.746337890625f); // 1.5^12
    const float sc[4] = { sb, sb * 1.5f, sb * 2.25f, sb * 3.375f };

    const uint32_t* tq = tab + ((uint32_t)q * 4u << 17);   // level 4q sub-table

    __syncthreads();   // ldsTab ready

    for (int g = blockIdx.x; g < nGroups; g += gridDim.x) {
        const int tile = g * 4 + wib;
        const int p = tile * 16 + n16;
        const float2 xy = ((const float2*)xin)[p];
        const float px = xy.x, py = xy.y;

        bf16x8 af;
#pragma unroll
        for (int lv = 0; lv < 4; ++lv) {
            const float posx = px * sc[lv], posy = py * sc[lv];
            const float fx = floorf(posx), fy = floorf(posy);
            const float frx = posx - fx,  fry = posy - fy;
            const uint32_t ix = (uint32_t)fx, iy = (uint32_t)fy;

            // which lanes of this lv-slot have an LDS-dense level (level = 4q+lv)
            bool cached; uint32_t W, doff;
            if (lv == 0) { cached = (q < 2);  W = (q == 0) ? 17u : 82u;
                           doff = (q == 0) ? 0u : 5308u; }
            else if (lv == 1) { cached = (q == 0); W = 25u; doff = 289u; }
            else if (lv == 2) { cached = (q == 0); W = 37u; doff = 914u; }
            else              { cached = (q == 0); W = 55u; doff = 2283u; }

            uint32_t u00, u10, u01, u11;
            if (cached) {
                const uint32_t a = doff + iy * W + ix;
                u00 = ldsTab[a];
                u10 = ldsTab[a + 1];
                u01 = ldsTab[a + W];
                u11 = ldsTab[a + W + 1];
            } else {
                const uint32_t hy0 = iy * PRIME, hy1 = hy0 + PRIME;
                const uint32_t i00 = ( ix       ^ hy0) & HMASK;
                const uint32_t i10 = ((ix + 1u) ^ hy0) & HMASK;
                const uint32_t i01 = ( ix       ^ hy1) & HMASK;
                const uint32_t i11 = ((ix + 1u) ^ hy1) & HMASK;
                const uint32_t base = (uint32_t)lv << 17;
                u00 = tq[base + i00];
                u10 = tq[base + i10];
                u01 = tq[base + i01];
                u11 = tq[base + i11];
            }

            const float wx1 = frx, wx0 = 1.0f - frx, wy1 = fry, wy0 = 1.0f - fry;
            const float w00 = wx0 * wy0, w10 = wx1 * wy0, w01 = wx0 * wy1, w11 = wx1 * wy1;
            const float f0 = w00 * bflo(u00) + w10 * bflo(u10) + w01 * bflo(u01) + w11 * bflo(u11);
            const float f1 = w00 * bfhi(u00) + w10 * bfhi(u10) + w01 * bfhi(u01) + w11 * bfhi(u11);
            af[2 * lv]     = (bf16_t)f0;
            af[2 * lv + 1] = (bf16_t)f1;
        }

        // ---- layer 0: [16x32] @ [32x64] + b0, relu ----
        f32x4 c0[4];
#pragma unroll
        for (int t = 0; t < 4; ++t) {
            f32x4 cc = { bv0[t], bv0[t], bv0[t], bv0[t] };
            c0[t] = __builtin_amdgcn_mfma_f32_16x16x32_bf16(af, Bw0[t], cc, 0, 0, 0);
        }

        __syncthreads();
#pragma unroll
        for (int t = 0; t < 4; ++t)
#pragma unroll
            for (int r = 0; r < 4; ++r)
                myLds[(q * 4 + r) * 80 + t * 16 + n16] = (bf16_t)fmaxf(c0[t][r], 0.0f);
        __syncthreads();

        bf16x8 A1[2];
#pragma unroll
        for (int c = 0; c < 2; ++c)
            A1[c] = *(const bf16x8*)&myLds[n16 * 80 + c * 32 + q * 8];

        // ---- layer 1: [16x64] @ [64x64] + b1, relu ----
        f32x4 c1[4];
#pragma unroll
        for (int t = 0; t < 4; ++t) {
            f32x4 cc = { bv1[t], bv1[t], bv1[t], bv1[t] };
            cc    = __builtin_amdgcn_mfma_f32_16x16x32_bf16(A1[0], Bw1[0][t], cc, 0, 0, 0);
            c1[t] = __builtin_amdgcn_mfma_f32_16x16x32_bf16(A1[1], Bw1[1][t], cc, 0, 0, 0);
        }

        __syncthreads();
#pragma unroll
        for (int t = 0; t < 4; ++t)
#pragma unroll
            for (int r = 0; r < 4; ++r)
                myLds[(q * 4 + r) * 80 + t * 16 + n16] = (bf16_t)fmaxf(c1[t][r], 0.0f);
        __syncthreads();

        bf16x8 A2[2];
#pragma unroll
        for (int c = 0; c < 2; ++c)
            A2[c] = *(const bf16x8*)&myLds[n16 * 80 + c * 32 + q * 8];

        // ---- layer 2: [16x64] @ [64x3 padded to 16] + b2 (no relu) ----
        f32x4 co = { bv2, bv2, bv2, bv2 };
        co = __builtin_amdgcn_mfma_f32_16x16x32_bf16(A2[0], Bw2[0], co, 0, 0, 0);
        co = __builtin_amdgcn_mfma_f32_16x16x32_bf16(A2[1], Bw2[1], co, 0, 0, 0);

        if (n16 < 3) {
#pragma unroll
            for (int r = 0; r < 4; ++r)
                out[(size_t)(tile * 16 + q * 4 + r) * 3 + n16] = co[r];
        }
    }
}

// ---- fallback (R2 known-good): direct fp32 gather, used only if ws too small
__global__ __launch_bounds__(256)
void fused_hash_mlp_fp32(const float* __restrict__ xin,
                         const float* __restrict__ enc,
                         const float* __restrict__ w0, const float* __restrict__ b0,
                         const float* __restrict__ w1, const float* __restrict__ b1,
                         const float* __restrict__ w2, const float* __restrict__ b2,
                         float* __restrict__ out,
                         int nGroups)
{
    __shared__ __align__(16) bf16_t lds[4 * 16 * 80];
    const int tid  = threadIdx.x;
    const int wib  = tid >> 6;
    const int lane = tid & 63;
    const int q    = lane >> 4;
    const int n16  = lane & 15;
    bf16_t* myLds = &lds[wib * (16 * 80)];

    bf16x8 Bw0[4], Bw1[2][4], Bw2[2];
#pragma unroll
    for (int t = 0; t < 4; ++t)
#pragma unroll
        for (int j = 0; j < 8; ++j)
            Bw0[t][j] = (bf16_t)w0[(q * 8 + j) * 64 + t * 16 + n16];
#pragma unroll
    for (int c = 0; c < 2; ++c)
#pragma unroll
        for (int t = 0; t < 4; ++t)
#pragma unroll
            for (int j = 0; j < 8; ++j)
                Bw1[c][t][j] = (bf16_t)w1[(c * 32 + q * 8 + j) * 64 + t * 16 + n16];
#pragma unroll
    for (int c = 0; c < 2; ++c)
#pragma unroll
        for (int j = 0; j < 8; ++j)
            Bw2[c][j] = (n16 < 3) ? (bf16_t)w2[(c * 32 + q * 8 + j) * 3 + n16]
                                  : (bf16_t)0.0f;

    float bv0[4], bv1[4];
#pragma unroll
    for (int t = 0; t < 4; ++t) { bv0[t] = b0[t * 16 + n16]; bv1[t] = b1[t * 16 + n16]; }
    const float bv2 = (n16 < 3) ? b2[n16] : 0.0f;

    const float sb = 16.0f * ((q == 0) ? 1.0f : (q == 1) ? 5.0625f :
                              (q == 2) ? 25.62890625f : 129.746337890625f);
    const float sc[4] = { sb, sb * 1.5f, sb * 2.25f, sb * 3.375f };
    const char* encB = (const char*)enc;
    const uint32_t lvBase = (uint32_t)q * 32u;

    for (int g = blockIdx.x; g < nGroups; g += gridDim.x) {
        const int tile = g * 4 + wib;
        const int p = tile * 16 + n16;
        const float2 xy = ((const float2*)xin)[p];
        const float px = xy.x, py = xy.y;

        bf16x8 af;
#pragma unroll
        for (int lv = 0; lv < 4; ++lv) {
            const float posx = px * sc[lv], posy = py * sc[lv];
            const float fx = floorf(posx), fy = floorf(posy);
            const float frx = posx - fx,  fry = posy - fy;
            const uint32_t ix = (uint32_t)fx, iy = (uint32_t)fy;
            const uint32_t hy0 = iy * PRIME, hy1 = hy0 + PRIME;
            const uint32_t i00 = ( ix       ^ hy0) & HMASK;
            const uint32_t i10 = ((ix + 1u) ^ hy0) & HMASK;
            const uint32_t i01 = ( ix       ^ hy1) & HMASK;
            const uint32_t i11 = ((ix + 1u) ^ hy1) & HMASK;
            const uint32_t off = lvBase + (uint32_t)lv * 8u;
            const float2 e00 = *(const float2*)(encB + (i00 * 128u + off));
            const float2 e10 = *(const float2*)(encB + (i10 * 128u + off));
            const float2 e01 = *(const float2*)(encB + (i01 * 128u + off));
            const float2 e11 = *(const float2*)(encB + (i11 * 128u + off));
            const float wx1 = frx, wx0 = 1.0f - frx, wy1 = fry, wy0 = 1.0f - fry;
            const float w00 = wx0 * wy0, w10 = wx1 * wy0, w01 = wx0 * wy1, w11 = wx1 * wy1;
            af[2 * lv]     = (bf16_t)(w00 * e00.x + w10 * e10.x + w01 * e01.x + w11 * e11.x);
            af[2 * lv + 1] = (bf16_t)(w00 * e00.y + w10 * e10.y + w01 * e01.y + w11 * e11.y);
        }

        f32x4 c0[4];
#pragma unroll
        for (int t = 0; t < 4; ++t) {
            f32x4 cc = { bv0[t], bv0[t], bv0[t], bv0[t] };
            c0[t] = __builtin_amdgcn_mfma_f32_16x16x32_bf16(af, Bw0[t], cc, 0, 0, 0);
        }
        __syncthreads();
#pragma unroll
        for (int t = 0; t < 4; ++t)
#pragma unroll
            for (int r = 0; r < 4; ++r)
                myLds[(q * 4 + r) * 80 + t * 16 + n16] = (bf16_t)fmaxf(c0[t][r], 0.0f);
        __syncthreads();
        bf16x8 A1[2];
#pragma unroll
        for (int c = 0; c < 2; ++c)
            A1[c] = *(const bf16x8*)&myLds[n16 * 80 + c * 32 + q * 8];

        f32x4 c1[4];
#pragma unroll
        for (int t = 0; t < 4; ++t) {
            f32x4 cc = { bv1[t], bv1[t], bv1[t], bv1[t] };
            cc    = __builtin_amdgcn_mfma_f32_16x16x32_bf16(A1[0], Bw1[0][t], cc, 0, 0, 0);
            c1[t] = __builtin_amdgcn_mfma_f32_16x16x32_bf16(A1[1], Bw1[1][t], cc, 0, 0, 0);
        }
        __syncthreads();
#pragma unroll
        for (int t = 0; t < 4; ++t)
#pragma unroll
            for (int r = 0; r < 4; ++r)
                myLds[(q * 4 + r) * 80 + t * 16 + n16] = (bf16_t)fmaxf(c1[t][r], 0.0f);
        __syncthreads();
        bf16x8 A2[2];
#pragma unroll
        for (int c = 0; c < 2; ++c)
            A2[c] = *(const bf16x8*)&myLds[n16 * 80 + c * 32 + q * 8];

        f32x4 co = { bv2, bv2, bv2, bv2 };
        co = __builtin_amdgcn_mfma_f32_16x16x32_bf16(A2[0], Bw2[0], co, 0, 0, 0);
        co = __builtin_amdgcn_mfma_f32_16x16x32_bf16(A2[1], Bw2[1], co, 0, 0, 0);
        if (n16 < 3) {
#pragma unroll
            for (int r = 0; r < 4; ++r)
                out[(size_t)(tile * 16 + q * 4 + r) * 3 + n16] = co[r];
        }
    }
}

extern "C" void kernel_launch(void* const* d_in, const int* in_sizes, int n_in,
                              void* d_out, int out_size, void* d_ws, size_t ws_size,
                              hipStream_t stream) {
    const float* x  = (const float*)d_in[0];
    const float* en = (const float*)d_in[1];
    const float* w0 = (const float*)d_in[2];
    const float* b0 = (const float*)d_in[3];
    const float* w1 = (const float*)d_in[4];
    const float* b1 = (const float*)d_in[5];
    const float* w2 = (const float*)d_in[6];
    const float* b2 = (const float*)d_in[7];
    float* out = (float*)d_out;

    const int N = in_sizes[0] / 2;      // 2^20 points
    const int nTiles  = N / 16;
    const int nGroups = nTiles / 4;     // 16384

    const size_t wsNeeded = ((size_t)TSIZE * 16 + NDENSE) * 4;   // ~8.44 MB
    if (ws_size >= wsNeeded) {
        uint32_t* tab   = (uint32_t*)d_ws;
        uint32_t* dense = tab + ((size_t)TSIZE * 16);
        repack_enc<<<(TSIZE * 16) / 256, 256, 0, stream>>>((const float2*)en, tab);
        densify_enc<<<NDENSE / 256, 256, 0, stream>>>((const float2*)en, dense);
        int blocks = 2048;
        if (blocks > nGroups) blocks = nGroups;
        fused_hash_mlp<<<blocks, 256, 0, stream>>>(x, tab, dense,
                                                   w0, b0, w1, b1, w2, b2, out, nGroups);
    } else {
        int blocks = 2048;
        if (blocks > nGroups) blocks = nGroups;
        fused_hash_mlp_fp32<<<blocks, 256, 0, stream>>>(x, en, w0, b0, w1, b1, w2, b2, out, nGroups);
    }
}